// Round 1
// baseline (419.070 us; speedup 1.0000x reference)
//
#include <hip/hip_runtime.h>

typedef unsigned short u16;
typedef __bf16 bf16x8 __attribute__((ext_vector_type(8)));
typedef float f32x4 __attribute__((ext_vector_type(4)));

#define HH  56
#define WW  56
#define HW  3136      // 56*56
#define CC  256
#define NB  8
#define CKP 2048      // c*7 padded to c*8 so each channel's 7 taps are one 16B chunk

// round-to-nearest-even fp32 -> bf16 (bit pattern)
__device__ __forceinline__ u16 f2bf(float f) {
  unsigned int u = __float_as_uint(f);
  u += 0x7fffu + ((u >> 16) & 1u);
  return (u16)(u >> 16);
}

// async global->LDS, 16B per lane; LDS dest is wave-uniform base + lane*16
__device__ __forceinline__ void lds_load16(const void* g, void* l) {
  __builtin_amdgcn_global_load_lds(
      (const __attribute__((address_space(1))) void*)g,
      (__attribute__((address_space(3))) void*)l, 16, 0, 0);
}

// ---------------------------------------------------------------------------
// pass1: t1 = p1w * x (fp32 buffer), xb = bf16(x).  Fully coalesced float4.
// grid = N*C*HW/4/256 = 6272 blocks
// ---------------------------------------------------------------------------
__global__ void pass1(const float* __restrict__ x, const float* __restrict__ p1w,
                      float* __restrict__ t1, u16* __restrict__ xb) {
  int i = blockIdx.x * 256 + threadIdx.x;        // over N*C*HW/4
  int cw = i % (CC * HW / 4);                    // p1w broadcast over n
  float4 xv = ((const float4*)x)[i];
  float4 wv = ((const float4*)p1w)[cw];
  float4 tv;
  tv.x = xv.x * wv.x; tv.y = xv.y * wv.y;
  tv.z = xv.z * wv.z; tv.w = xv.w * wv.w;
  ((float4*)t1)[i] = tv;
  unsigned int lo = (unsigned)f2bf(xv.x) | ((unsigned)f2bf(xv.y) << 16);
  unsigned int hi = (unsigned)f2bf(xv.z) | ((unsigned)f2bf(xv.w) << 16);
  ((uint2*)xb)[i] = make_uint2(lo, hi);
}

// ---------------------------------------------------------------------------
// pass2: t5[(n)][j*8+k][p] = bf16(t1[n,j,p] - t1[n,(j-1)%C, h, w+k-3 (0-pad)])
// k = 0..6; pad rows j*8+7 left untouched (finite poison, outputs overwritten).
// thread <-> (n,j,p): reads coalesced + 7-tap window (L1), writes coalesced.
// grid = N*C*HW/256 = 25088
// ---------------------------------------------------------------------------
__global__ void pass2(const float* __restrict__ t1, u16* __restrict__ t5) {
  int idx = blockIdx.x * 256 + threadIdx.x;
  int p   = idx % HW;
  int rem = idx / HW;            // n*C + j
  int j   = rem & (CC - 1);
  int n   = rem >> 8;
  int h = p / WW, w = p - h * WW;
  int jm = (j + CC - 1) & (CC - 1);
  const float* t1n  = t1 + (long)(n * CC) * HW;
  float a           = t1n[(long)j * HW + p];
  const float* rowm = t1n + (long)jm * HW + h * WW;
  u16* out = t5 + ((long)n * CKP + j * 8) * HW + p;
#pragma unroll
  for (int k = 0; k < 7; ++k) {
    int tap = w + k - 3;
    float t3v = ((unsigned)tap < (unsigned)WW) ? rowm[tap] : 0.f;
    out[(long)k * HW] = f2bf(a - t3v);
  }
}

// ---------------------------------------------------------------------------
// pass3: t6T[n][p][j*8+k] = bf16(x[n,j,p] + t2p[n,(j-1)%C,(h-1)%56,((w+1)%56)+k-3])
// slot 7 = 0.  Block = (p,n), lane = j -> one 16B coalesced store per thread.
// grid = (3136, 8)
// ---------------------------------------------------------------------------
__global__ void pass3(const float* __restrict__ x, const float* __restrict__ t1,
                      u16* __restrict__ t6T) {
  const int p = blockIdx.x, n = blockIdx.y;
  const int j = threadIdx.x;
  const int h = p / WW, w = p - h * WW;
  const int h2 = (h + HH - 1) % HH;      // roll +1 on h: source row h-1
  const int w2 = (w + 1) % WW;           // roll -1 on w: source col w+1
  const int jm = (j + CC - 1) & (CC - 1);
  const float xv    = x[((long)(n * CC + j)) * HW + p];
  const float* rowm = t1 + ((long)(n * CC + jm)) * HW + h2 * WW;
  u16 v[8];
#pragma unroll
  for (int k = 0; k < 7; ++k) {
    int tap = w2 + k - 3;
    float t4v = ((unsigned)tap < (unsigned)WW) ? rowm[tap] : 0.f;
    v[k] = f2bf(xv + t4v);
  }
  v[7] = 0;
  uint4 q = make_uint4(v[0] | ((unsigned)v[1] << 16),
                       v[2] | ((unsigned)v[3] << 16),
                       v[4] | ((unsigned)v[5] << 16),
                       v[6] | ((unsigned)v[7] << 16));
  *(uint4*)&t6T[((long)(n * HW + p)) * CKP + j * 8] = q;
}

// ---------------------------------------------------------------------------
// NT GEMM, bf16 MFMA 16x16x32, 128x128 tile, BK=64, global_load_lds staging,
// XOR chunk swizzle in LDS.  C[m][nn] = scale * sum_k A[m][k]*B[nn][k].
// IS1: A=xb(256x3136) B=t5(2048x3136) -> t7 bf16 (256x2048), zero pad cols.
// !IS1: A=t7(256x2048) B=t6T(3136x2048) -> d_out fp32 (256x3136), col guard.
// ---------------------------------------------------------------------------
template <int IS1>
__global__ __launch_bounds__(256)
void gemm_nt(const u16* __restrict__ A, const u16* __restrict__ B,
             void* __restrict__ Co) {
  constexpr int  LDA = IS1 ? HW : CKP;
  constexpr int  LDB = IS1 ? HW : CKP;
  constexpr int  KD  = IS1 ? HW : CKP;
  constexpr int  LDC = IS1 ? CKP : HW;
  constexpr long sA  = IS1 ? (long)CC * HW : (long)CC * CKP;
  constexpr long sB  = IS1 ? (long)CKP * HW : (long)HW * CKP;
  constexpr long sC  = IS1 ? (long)CC * CKP : (long)CC * HW;
  const float scale  = IS1 ? (1.0f / 56.0f) : 0.023622783f;  // 1/sqrt(hw), 1/sqrt(1792)

  __shared__ u16 As[128 * 64];
  __shared__ u16 Bs[128 * 64];

  const int nb = blockIdx.z;
  const u16* Ab = A + nb * sA;
  const u16* Bb = B + nb * sB;
  const int m0 = blockIdx.x * 128, n0 = blockIdx.y * 128;
  const int t = threadIdx.x;
  const int lane = t & 63, wave = t >> 6;
  const int wm = wave & 1, wn = wave >> 1;     // 2x2 waves, 64x64 each
  const int lm = lane & 15, quad = lane >> 4;

  f32x4 acc[4][4];
#pragma unroll
  for (int a = 0; a < 4; ++a)
#pragma unroll
    for (int b = 0; b < 4; ++b) acc[a][b] = (f32x4)0.0f;

  // staging geometry: 1024 chunks of 16B per tile, 4 per thread.
  int rowc[4], colc[4];
#pragma unroll
  for (int ci = 0; ci < 4; ++ci) {
    int c = t + ci * 256;
    rowc[ci] = c >> 3;
    colc[ci] = ((c & 7) ^ (rowc[ci] & 7)) * 8;   // XOR swizzle breaks bank aliasing
  }

  for (int k0 = 0; k0 < KD; k0 += 64) {
#pragma unroll
    for (int ci = 0; ci < 4; ++ci) {
      int c = t + ci * 256;
      lds_load16(Ab + (long)(m0 + rowc[ci]) * LDA + k0 + colc[ci], &As[c * 8]);
      int br = n0 + rowc[ci];
      if (!IS1) br = br < (HW - 1) ? br : (HW - 1);   // clamp rows past 3135
      lds_load16(Bb + (long)br * LDB + k0 + colc[ci], &Bs[c * 8]);
    }
    __syncthreads();   // compiler drains vmcnt before barrier
#pragma unroll
    for (int kk = 0; kk < 2; ++kk) {
      const int phys = ((kk * 4 + quad) ^ (lm & 7)) * 8;  // swizzled chunk, elems
      bf16x8 af[4], bv[4];
#pragma unroll
      for (int mi = 0; mi < 4; ++mi)
        af[mi] = *(const bf16x8*)&As[(wm * 64 + mi * 16 + lm) * 64 + phys];
#pragma unroll
      for (int ni = 0; ni < 4; ++ni)
        bv[ni] = *(const bf16x8*)&Bs[(wn * 64 + ni * 16 + lm) * 64 + phys];
#pragma unroll
      for (int mi = 0; mi < 4; ++mi)
#pragma unroll
        for (int ni = 0; ni < 4; ++ni)
          acc[mi][ni] = __builtin_amdgcn_mfma_f32_16x16x32_bf16(
              af[mi], bv[ni], acc[mi][ni], 0, 0, 0);
    }
    __syncthreads();
  }

  // epilogue; C/D layout (m89-verified): col = lane&15, row = quad*4 + reg
  if constexpr (IS1) {
    u16* Cb = (u16*)Co + nb * sC;
    const bool padl = (lm & 7) == 7;   // pad columns jk%8==7 must be exact zero
#pragma unroll
    for (int mi = 0; mi < 4; ++mi)
#pragma unroll
      for (int ni = 0; ni < 4; ++ni) {
        int rb = m0 + wm * 64 + mi * 16 + quad * 4;
        int cg = n0 + wn * 64 + ni * 16 + lm;
#pragma unroll
        for (int r = 0; r < 4; ++r)
          Cb[(long)(rb + r) * LDC + cg] = padl ? (u16)0 : f2bf(acc[mi][ni][r] * scale);
      }
  } else {
    float* Cb = (float*)Co + nb * sC;
#pragma unroll
    for (int mi = 0; mi < 4; ++mi)
#pragma unroll
      for (int ni = 0; ni < 4; ++ni) {
        int rb = m0 + wm * 64 + mi * 16 + quad * 4;
        int cg = n0 + wn * 64 + ni * 16 + lm;
        if (cg < HW) {
#pragma unroll
          for (int r = 0; r < 4; ++r)
            Cb[(long)(rb + r) * LDC + cg] = acc[mi][ni][r] * scale;
        }
      }
  }
}

// ---------------------------------------------------------------------------
extern "C" void kernel_launch(void* const* d_in, const int* in_sizes, int n_in,
                              void* d_out, int out_size, void* d_ws, size_t ws_size,
                              hipStream_t stream) {
  const float* x   = (const float*)d_in[0];   // (8,256,56,56)
  const float* p1w = (const float*)d_in[1];   // (1,256,56,56)

  char* ws = (char*)d_ws;
  size_t o = 0;
  float* t1  = (float*)(ws + o); o += (size_t)NB * CC * HW * 4;   //  25.7 MB
  u16*   xb  = (u16*)(ws + o);   o += (size_t)NB * CC * HW * 2;   //  12.8 MB
  u16*   t5  = (u16*)(ws + o);   o += (size_t)NB * CKP * HW * 2;  // 102.8 MB
  u16*   t6T = (u16*)(ws + o);   o += (size_t)NB * HW * CKP * 2;  // 102.8 MB
  u16*   t7  = (u16*)(ws + o);   o += (size_t)NB * CC * CKP * 2;  //   8.4 MB
  // total 252,444,672 bytes

  pass1<<<NB * CC * HW / 4 / 256, 256, 0, stream>>>(x, p1w, t1, xb);
  pass2<<<NB * CC * HW / 256, 256, 0, stream>>>(t1, t5);
  pass3<<<dim3(HW, NB), 256, 0, stream>>>(x, t1, t6T);
  gemm_nt<1><<<dim3(2, CKP / 128, NB), 256, 0, stream>>>(xb, t5, t7);
  gemm_nt<0><<<dim3(2, (HW + 127) / 128, NB), 256, 0, stream>>>(t7, t6T, d_out);
}

// Round 2
// 306.049 us; speedup vs baseline: 1.3693x; 1.3693x over previous
//
#include <hip/hip_runtime.h>

typedef unsigned short u16;
typedef __bf16 bf16x8 __attribute__((ext_vector_type(8)));
typedef float f32x4 __attribute__((ext_vector_type(4)));

#define HH  56
#define WW  56
#define HW  3136      // 56*56
#define CC  256
#define NB  8
#define CKP 2048      // c*7 padded to c*8 so each channel's 7 taps are one 16B chunk

// round-to-nearest-even fp32 -> bf16 (bit pattern)
__device__ __forceinline__ u16 f2bf(float f) {
  unsigned int u = __float_as_uint(f);
  u += 0x7fffu + ((u >> 16) & 1u);
  return (u16)(u >> 16);
}

// async global->LDS, 16B per lane; LDS dest is wave-uniform base + lane*16
__device__ __forceinline__ void lds_load16(const void* g, void* l) {
  __builtin_amdgcn_global_load_lds(
      (const __attribute__((address_space(1))) void*)g,
      (__attribute__((address_space(3))) void*)l, 16, 0, 0);
}

// ---------------------------------------------------------------------------
// pass1: t1 = p1w * x (fp32 buffer), xb = bf16(x).  Fully coalesced float4.
// grid = N*C*HW/4/256 = 6272 blocks
// ---------------------------------------------------------------------------
__global__ void pass1(const float* __restrict__ x, const float* __restrict__ p1w,
                      float* __restrict__ t1, u16* __restrict__ xb) {
  int i = blockIdx.x * 256 + threadIdx.x;        // over N*C*HW/4
  int cw = i % (CC * HW / 4);                    // p1w broadcast over n
  float4 xv = ((const float4*)x)[i];
  float4 wv = ((const float4*)p1w)[cw];
  float4 tv;
  tv.x = xv.x * wv.x; tv.y = xv.y * wv.y;
  tv.z = xv.z * wv.z; tv.w = xv.w * wv.w;
  ((float4*)t1)[i] = tv;
  unsigned int lo = (unsigned)f2bf(xv.x) | ((unsigned)f2bf(xv.y) << 16);
  unsigned int hi = (unsigned)f2bf(xv.z) | ((unsigned)f2bf(xv.w) << 16);
  ((uint2*)xb)[i] = make_uint2(lo, hi);
}

// ---------------------------------------------------------------------------
// pass2: t5[(n)][j*8+k][p] = bf16(t1[n,j,p] - t1[n,(j-1)%C, h, w+k-3 (0-pad)])
// k = 0..6; pad rows j*8+7 left untouched (finite poison, outputs overwritten).
// thread <-> (n,j,p): reads coalesced + 7-tap window (L1), writes coalesced.
// grid = N*C*HW/256 = 25088
// ---------------------------------------------------------------------------
__global__ void pass2(const float* __restrict__ t1, u16* __restrict__ t5) {
  int idx = blockIdx.x * 256 + threadIdx.x;
  int p   = idx % HW;
  int rem = idx / HW;            // n*C + j
  int j   = rem & (CC - 1);
  int n   = rem >> 8;
  int h = p / WW, w = p - h * WW;
  int jm = (j + CC - 1) & (CC - 1);
  const float* t1n  = t1 + (long)(n * CC) * HW;
  float a           = t1n[(long)j * HW + p];
  const float* rowm = t1n + (long)jm * HW + h * WW;
  u16* out = t5 + ((long)n * CKP + j * 8) * HW + p;
#pragma unroll
  for (int k = 0; k < 7; ++k) {
    int tap = w + k - 3;
    float t3v = ((unsigned)tap < (unsigned)WW) ? rowm[tap] : 0.f;
    out[(long)k * HW] = f2bf(a - t3v);
  }
}

// ---------------------------------------------------------------------------
// pass3 (LDS transpose): t6T[n][p][j*8+k] =
//   bf16(x[n,j,p] + t1[n,(j-1)%C,(h-1)%56,((w+1)%56)+k-3]),  slot 7 = 0.
// Block = (8 p-values, n); 256 thr = 8 p-lanes x 32 j-subs.
// Phase 1: lanes along p -> coalesced reads; pack 16B chunks into LDS tile.
// Phase 2: coalesced 4KB-per-p writes of t6T from LDS.
// LDS row stride 2056 u16 (+8 pad) rotates banks by 4 per p-row.
// grid = (HW/8=392, NB)
// ---------------------------------------------------------------------------
#define P3P  8                  // p-values per block
#define P3S  (CKP + 8)          // LDS row stride in u16
__global__ __launch_bounds__(256)
void pass3(const float* __restrict__ x, const float* __restrict__ t1,
           u16* __restrict__ t6T) {
  __shared__ u16 tile[P3P * P3S];   // 32.9 KB
  const int n  = blockIdx.y;
  const int p0 = blockIdx.x * P3P;
  const int t  = threadIdx.x;

  // ---- phase 1: compute, lanes along p ----
  {
    const int pl = t & (P3P - 1);       // p lane 0..7
    const int js = t >> 3;              // j sub 0..31
    const int p  = p0 + pl;
    const int h  = p / WW, w = p - h * WW;
    const int h2 = (h + HH - 1) % HH;   // roll +1 on h: source row h-1
    const int w2 = (w + 1) % WW;        // roll -1 on w: source col w+1
    const float* xn  = x  + (long)n * CC * HW;
    const float* t1n = t1 + (long)n * CC * HW;
#pragma unroll
    for (int jo = 0; jo < CC / 32; ++jo) {
      const int j  = jo * 32 + js;
      const int jm = (j + CC - 1) & (CC - 1);
      const float xv    = xn[(long)j * HW + p];
      const float* rowm = t1n + (long)jm * HW + h2 * WW;
      u16 v[8];
#pragma unroll
      for (int k = 0; k < 7; ++k) {
        int tap = w2 + k - 3;
        float t4v = ((unsigned)tap < (unsigned)WW) ? rowm[tap] : 0.f;
        v[k] = f2bf(xv + t4v);
      }
      v[7] = 0;
      uint4 q = make_uint4(v[0] | ((unsigned)v[1] << 16),
                           v[2] | ((unsigned)v[3] << 16),
                           v[4] | ((unsigned)v[5] << 16),
                           v[6] | ((unsigned)v[7] << 16));
      *(uint4*)&tile[pl * P3S + j * 8] = q;
    }
  }
  __syncthreads();

  // ---- phase 2: coalesced write-out ----
  {
    const int pp = t >> 5;              // p row 0..7
    const int c  = t & 31;              // chunk lane 0..31
    u16* outp = t6T + ((long)(n * HW + p0 + pp)) * CKP;
    const u16* srcp = &tile[pp * P3S];
#pragma unroll
    for (int ci = 0; ci < 8; ++ci) {
      int chunk = c + ci * 32;          // 256 chunks of 16B per p-row
      *(uint4*)&outp[chunk * 8] = *(const uint4*)&srcp[chunk * 8];
    }
  }
}

// ---------------------------------------------------------------------------
// NT GEMM, bf16 MFMA 16x16x32, 128x128 tile, BK=64, global_load_lds staging,
// XOR chunk swizzle in LDS.  C[m][nn] = scale * sum_k A[m][k]*B[nn][k].
// IS1: A=xb(256x3136) B=t5(2048x3136) -> t7 bf16 (256x2048), zero pad cols.
// !IS1: A=t7(256x2048) B=t6T(3136x2048) -> d_out fp32 (256x3136), col guard.
// ---------------------------------------------------------------------------
template <int IS1>
__global__ __launch_bounds__(256)
void gemm_nt(const u16* __restrict__ A, const u16* __restrict__ B,
             void* __restrict__ Co) {
  constexpr int  LDA = IS1 ? HW : CKP;
  constexpr int  LDB = IS1 ? HW : CKP;
  constexpr int  KD  = IS1 ? HW : CKP;
  constexpr int  LDC = IS1 ? CKP : HW;
  constexpr long sA  = IS1 ? (long)CC * HW : (long)CC * CKP;
  constexpr long sB  = IS1 ? (long)CKP * HW : (long)HW * CKP;
  constexpr long sC  = IS1 ? (long)CC * CKP : (long)CC * HW;
  const float scale  = IS1 ? (1.0f / 56.0f) : 0.023622783f;  // 1/sqrt(hw), 1/sqrt(1792)

  __shared__ u16 As[128 * 64];
  __shared__ u16 Bs[128 * 64];

  const int nb = blockIdx.z;
  const u16* Ab = A + nb * sA;
  const u16* Bb = B + nb * sB;
  const int m0 = blockIdx.x * 128, n0 = blockIdx.y * 128;
  const int t = threadIdx.x;
  const int lane = t & 63, wave = t >> 6;
  const int wm = wave & 1, wn = wave >> 1;     // 2x2 waves, 64x64 each
  const int lm = lane & 15, quad = lane >> 4;

  f32x4 acc[4][4];
#pragma unroll
  for (int a = 0; a < 4; ++a)
#pragma unroll
    for (int b = 0; b < 4; ++b) acc[a][b] = (f32x4)0.0f;

  // staging geometry: 1024 chunks of 16B per tile, 4 per thread.
  int rowc[4], colc[4];
#pragma unroll
  for (int ci = 0; ci < 4; ++ci) {
    int c = t + ci * 256;
    rowc[ci] = c >> 3;
    colc[ci] = ((c & 7) ^ (rowc[ci] & 7)) * 8;   // XOR swizzle breaks bank aliasing
  }

  for (int k0 = 0; k0 < KD; k0 += 64) {
#pragma unroll
    for (int ci = 0; ci < 4; ++ci) {
      int c = t + ci * 256;
      lds_load16(Ab + (long)(m0 + rowc[ci]) * LDA + k0 + colc[ci], &As[c * 8]);
      int br = n0 + rowc[ci];
      if (!IS1) br = br < (HW - 1) ? br : (HW - 1);   // clamp rows past 3135
      lds_load16(Bb + (long)br * LDB + k0 + colc[ci], &Bs[c * 8]);
    }
    __syncthreads();   // compiler drains vmcnt before barrier
#pragma unroll
    for (int kk = 0; kk < 2; ++kk) {
      const int phys = ((kk * 4 + quad) ^ (lm & 7)) * 8;  // swizzled chunk, elems
      bf16x8 af[4], bv[4];
#pragma unroll
      for (int mi = 0; mi < 4; ++mi)
        af[mi] = *(const bf16x8*)&As[(wm * 64 + mi * 16 + lm) * 64 + phys];
#pragma unroll
      for (int ni = 0; ni < 4; ++ni)
        bv[ni] = *(const bf16x8*)&Bs[(wn * 64 + ni * 16 + lm) * 64 + phys];
#pragma unroll
      for (int mi = 0; mi < 4; ++mi)
#pragma unroll
        for (int ni = 0; ni < 4; ++ni)
          acc[mi][ni] = __builtin_amdgcn_mfma_f32_16x16x32_bf16(
              af[mi], bv[ni], acc[mi][ni], 0, 0, 0);
    }
    __syncthreads();
  }

  // epilogue; C/D layout (m89-verified): col = lane&15, row = quad*4 + reg
  if constexpr (IS1) {
    u16* Cb = (u16*)Co + nb * sC;
    const bool padl = (lm & 7) == 7;   // pad columns jk%8==7 must be exact zero
#pragma unroll
    for (int mi = 0; mi < 4; ++mi)
#pragma unroll
      for (int ni = 0; ni < 4; ++ni) {
        int rb = m0 + wm * 64 + mi * 16 + quad * 4;
        int cg = n0 + wn * 64 + ni * 16 + lm;
#pragma unroll
        for (int r = 0; r < 4; ++r)
          Cb[(long)(rb + r) * LDC + cg] = padl ? (u16)0 : f2bf(acc[mi][ni][r] * scale);
      }
  } else {
    float* Cb = (float*)Co + nb * sC;
#pragma unroll
    for (int mi = 0; mi < 4; ++mi)
#pragma unroll
      for (int ni = 0; ni < 4; ++ni) {
        int rb = m0 + wm * 64 + mi * 16 + quad * 4;
        int cg = n0 + wn * 64 + ni * 16 + lm;
        if (cg < HW) {
#pragma unroll
          for (int r = 0; r < 4; ++r)
            Cb[(long)(rb + r) * LDC + cg] = acc[mi][ni][r] * scale;
        }
      }
  }
}

// ---------------------------------------------------------------------------
extern "C" void kernel_launch(void* const* d_in, const int* in_sizes, int n_in,
                              void* d_out, int out_size, void* d_ws, size_t ws_size,
                              hipStream_t stream) {
  const float* x   = (const float*)d_in[0];   // (8,256,56,56)
  const float* p1w = (const float*)d_in[1];   // (1,256,56,56)

  char* ws = (char*)d_ws;
  size_t o = 0;
  float* t1  = (float*)(ws + o); o += (size_t)NB * CC * HW * 4;   //  25.7 MB
  u16*   xb  = (u16*)(ws + o);   o += (size_t)NB * CC * HW * 2;   //  12.8 MB
  u16*   t5  = (u16*)(ws + o);   o += (size_t)NB * CKP * HW * 2;  // 102.8 MB
  u16*   t6T = (u16*)(ws + o);   o += (size_t)NB * HW * CKP * 2;  // 102.8 MB
  u16*   t7  = (u16*)(ws + o);   o += (size_t)NB * CC * CKP * 2;  //   8.4 MB
  // total 252,444,672 bytes

  pass1<<<NB * CC * HW / 4 / 256, 256, 0, stream>>>(x, p1w, t1, xb);
  pass2<<<NB * CC * HW / 256, 256, 0, stream>>>(t1, t5);
  pass3<<<dim3(HW / P3P, NB), 256, 0, stream>>>(x, t1, t6T);
  gemm_nt<1><<<dim3(2, CKP / 128, NB), 256, 0, stream>>>(xb, t5, t7);
  gemm_nt<0><<<dim3(2, (HW + 127) / 128, NB), 256, 0, stream>>>(t7, t6T, d_out);
}